// Round 18
// baseline (546.631 us; speedup 1.0000x reference)
//
#include <hip/hip_runtime.h>
#include <math.h>

// Problem constants
#define N_IMAGE   128
#define N_CAPTION 32
#define N_REGION  36
#define N_WORD    24
#define EMBED     1024
#define EPSV      1e-8f

// Workspace layout (float offsets)
#define WS_W1 0            // 64*64 weight-normed out1 W
#define WS_W2 4096         // 64 weight-normed out2 row
#define WS_S  4160         // 32 captions * 24 words * 8 kernels
#define WS_QN 10304        // 32 captions * 24 words * 32 blocks

// ---------------------------------------------------------------------------
// Kernel 1+2 merged: block 32 = weight-norm; blocks 0..31 = per-caption
// precompute (words_sim softmax, adjacency, S[i][k], block-norms qn).
// ---------------------------------------------------------------------------
__global__ __launch_bounds__(256) void cap_prep_k(
    const float* __restrict__ captions, const int* __restrict__ depends,
    const float* __restrict__ mean_k, const float* __restrict__ prec_k,
    const float* __restrict__ v1, const float* __restrict__ g1,
    const float* __restrict__ v2, const float* __restrict__ g2,
    float* __restrict__ ws) {
  __shared__ __align__(16) float capT[24][132];
  __shared__ float partB[2304];   // 4 groups * 576
  __shared__ float wsL[24][25];
  __shared__ float adjL[24][24];

  const int tid = threadIdx.x;
  if (blockIdx.x == 32) {   // weight-norm branch (R18 merge; no barriers here)
    if (tid < 64) {
      const int j = tid;
      float s = 0.f;
      for (int c0 = 0; c0 < 64; c0++) { float x = v1[j * 64 + c0]; s += x * x; }
      const float sc = g1[j] / sqrtf(s);
      for (int c0 = 0; c0 < 64; c0++) ws[WS_W1 + j * 64 + c0] = v1[j * 64 + c0] * sc;
      float s2 = 0.f;
      for (int c0 = 0; c0 < 64; c0++) { float x = v2[c0]; s2 += x * x; }
      ws[WS_W2 + j] = v2[j] * (g2[0] / sqrtf(s2));
    }
    return;
  }

  const int c = blockIdx.x;
  const float* capC = captions + c * N_WORD * EMBED;

  const int g = tid / 36, t = tid % 36;
  const int i0 = (t / 6) * 4, j0 = (t % 6) * 4;
  const bool act = tid < 144;
  float acc[4][4] = {};
  for (int k0 = 0; k0 < EMBED; k0 += 128) {
    for (int idx = tid; idx < 24 * 32; idx += 256) {
      int r = idx >> 5, q = idx & 31;
      *(float4*)&capT[r][q * 4] = *(const float4*)(capC + r * EMBED + k0 + q * 4);
    }
    __syncthreads();
    if (act) {
#pragma unroll
      for (int q8 = 0; q8 < 8; q8++) {
        const int q = g * 8 + q8;
        float4 av[4], bv[4];
#pragma unroll
        for (int a = 0; a < 4; a++) av[a] = *(const float4*)&capT[i0 + a][q * 4];
#pragma unroll
        for (int b = 0; b < 4; b++) bv[b] = *(const float4*)&capT[j0 + b][q * 4];
#pragma unroll
        for (int a = 0; a < 4; a++)
#pragma unroll
          for (int b = 0; b < 4; b++)
            acc[a][b] += av[a].x * bv[b].x + av[a].y * bv[b].y +
                         av[a].z * bv[b].z + av[a].w * bv[b].w;
      }
    }
    __syncthreads();
  }
  if (act)
#pragma unroll
    for (int a = 0; a < 4; a++)
#pragma unroll
      for (int b = 0; b < 4; b++)
        partB[g * 576 + (i0 + a) * 24 + (j0 + b)] = acc[a][b];
  __syncthreads();
  for (int p = tid; p < 576; p += 256)
    wsL[p / 24][p % 24] = partB[p] + partB[p + 576] + partB[p + 1152] + partB[p + 1728];
  {
    float* ap = &adjL[0][0];
    for (int p = tid; p < 576; p += 256) ap[p] = 0.f;
  }
  __syncthreads();
  if (tid < 24) {
    const int i = tid;
    float m = -1e30f;
    for (int j = 0; j < 24; j++) m = fmaxf(m, wsL[i][j]);
    float ssum = 0.f;
    for (int j = 0; j < 24; j++) {
      float e = expf(4.0f * (wsL[i][j] - m));
      wsL[i][j] = e; ssum += e;
    }
    float inv = 1.0f / ssum;
    for (int j = 0; j < 24; j++) wsL[i][j] *= inv;
  }
  __syncthreads();
  if (tid >= 1 && tid < 23) {
    int r = depends[c * 46 + tid * 2];
    int cc = depends[c * 46 + tid * 2 + 1];
    if ((unsigned)r < 24u && (unsigned)cc < 24u) {
      adjL[r][cc] = 1.f;
      adjL[cc][r] = 1.f;
    }
  }
  __syncthreads();
  if (tid < 24) adjL[tid][tid] += 1.f;
  __syncthreads();
  if (tid < 24) {
    const int i = tid;
    float mk[8], pk2[8];
#pragma unroll
    for (int k = 0; k < 8; k++) {
      mk[k] = mean_k[k];
      float p = prec_k[k];
      pk2[k] = 1e-14f + p * p;
    }
    float s2 = 0.f;
    for (int j = 0; j < 24; j++) {
      float a = adjL[i][j] * wsL[i][j];
      s2 += a * a;
    }
    const float inv = 1.0f / (sqrtf(s2) + EPSV);
    float accS[8] = {};
    for (int j = 0; j < 24; j++) {
      const float adj_ij = adjL[i][j];
      if (adj_ij != 0.f) {
        const float nb = adj_ij * wsL[i][j] * inv;
        float wk[8], ssum = 0.f;
#pragma unroll
        for (int k = 0; k < 8; k++) {
          float d = nb - mk[k];
          wk[k] = expf(-0.5f * d * d / pk2[k]);
          ssum += wk[k];
        }
        const float invs = adj_ij / ssum;
#pragma unroll
        for (int k = 0; k < 8; k++) accS[k] += wk[k] * invs;
      }
    }
#pragma unroll
    for (int k = 0; k < 8; k++) ws[WS_S + (c * 24 + i) * 8 + k] = accS[k];
  }
  for (int p = tid; p < 768; p += 256) {
    const int w = p >> 5, f = p & 31;
    const float* q = capC + w * EMBED + f * 32;
    float s = 0.f;
#pragma unroll
    for (int d = 0; d < 32; d += 4) {
      float4 v = *(const float4*)(q + d);
      s += v.x * v.x + v.y * v.y + v.z * v.z + v.w * v.w;
    }
    ws[WS_QN + (c * 24 + w) * 32 + f] = sqrtf(s);
  }
}

// ---------------------------------------------------------------------------
// Kernel 3: main — one block per (image n, caption-PAIR c0,c0+1). R18:
//   R17 (423us, VGPR 68, VALU 62.6%) + T14 register-prefetch on STAGE 1:
//   chunk k+1's global loads (5 img + 6 cap float4 = 44 VGPR in flight)
//   issue right after the compute barrier and land in LDS at the top of the
//   next iteration — staging latency hides under the 16K-cycle GEMM.
//   Barriers unchanged (2/chunk), LDS unchanged (52.4KB, 3 blk/CU).
//   Est VGPR ~100-115 (cap 128; if spill -> revert to R17).
//   Front kernels merged (cap_prep block 32 = weight-norm): one less launch.
// ---------------------------------------------------------------------------
__global__ __launch_bounds__(256, 2) void main_k(
    const float* __restrict__ images, const float* __restrict__ captions,
    const float* __restrict__ conv_w, const float* __restrict__ out1_b,
    const float* __restrict__ out2_b, const float* __restrict__ ws,
    float* __restrict__ out) {
  // bufA: img chunk A (swizzled 36x132) / split-K partials (3456) / W1t (64x68)
  // bufB: capT 2 captions (48x132) / {tnode[2][24][33], img chunk B / hid2}
  // bufC: attn [2][36][28] / {Ss[384], w2s[64], b1s[64], sred[48]}
  __shared__ __align__(16) float bufA[36 * 132];      // 19008 B
  __shared__ __align__(16) float bufB[48 * 132];      // 25344 B
  __shared__ __align__(16) float bufC[2 * 36 * 28];   //  8064 B => 52416 B

  const int tid = threadIdx.x;
  const int bid = blockIdx.x;
  const int n = bid >> 4, c0 = (bid & 15) * 2;
  const float* imgN = images + n * N_REGION * EMBED;
  const float* capB = captions + c0 * N_WORD * EMBED;  // 48 contiguous rows

  // ============ stage 1: attn_raw = leaky_relu(img @ [cap0;cap1]^T) ============
  // 216 active threads, 2-way split-K, 4x4 register tiles over 36x48 outputs.
  // T14: global loads for chunk k+1 in registers while chunk k computes.
  const int g1 = tid / 108, t1 = tid % 108;
  const int r0 = (t1 / 12) * 4, w0 = (t1 % 12) * 4;
  const bool act1 = tid < 216;
  const int si = (r0 >> 2) & 7, sc = (w0 >> 2) & 7;   // bank swizzles
  float acc1[4][4] = {};

  {
    float4 pimg[5], pcap[6];
    // prologue: issue chunk-0 loads
#pragma unroll
    for (int i = 0; i < 4; i++) {
      const int idx = tid + i * 256;
      pimg[i] = *(const float4*)(imgN + (idx >> 5) * EMBED + (idx & 31) * 4);
    }
    if (tid < 128) {
      const int idx = tid + 1024;
      pimg[4] = *(const float4*)(imgN + (idx >> 5) * EMBED + (idx & 31) * 4);
    }
#pragma unroll
    for (int i = 0; i < 6; i++) {
      const int idx = tid + i * 256;
      pcap[i] = *(const float4*)(capB + (idx >> 5) * EMBED + (idx & 31) * 4);
    }
    for (int kc = 0; kc < 8; kc++) {
      // land prefetched chunk kc in LDS
#pragma unroll
      for (int i = 0; i < 4; i++) {
        const int idx = tid + i * 256;
        const int r = idx >> 5, q = idx & 31;
        *(float4*)&bufA[r * 132 + (q ^ ((r >> 2) & 7)) * 4] = pimg[i];
      }
      if (tid < 128) {
        const int idx = tid + 1024;
        const int r = idx >> 5, q = idx & 31;
        *(float4*)&bufA[r * 132 + (q ^ ((r >> 2) & 7)) * 4] = pimg[4];
      }
#pragma unroll
      for (int i = 0; i < 6; i++) {
        const int idx = tid + i * 256;
        const int r = idx >> 5, q = idx & 31;
        *(float4*)&bufB[r * 132 + (q ^ ((r >> 2) & 7)) * 4] = pcap[i];
      }
      __syncthreads();
      // issue chunk kc+1 loads; latency hides under the GEMM below
      if (kc < 7) {
        const int kn = (kc + 1) * 128;
#pragma unroll
        for (int i = 0; i < 4; i++) {
          const int idx = tid + i * 256;
          pimg[i] = *(const float4*)(imgN + (idx >> 5) * EMBED + kn + (idx & 31) * 4);
        }
        if (tid < 128) {
          const int idx = tid + 1024;
          pimg[4] = *(const float4*)(imgN + (idx >> 5) * EMBED + kn + (idx & 31) * 4);
        }
#pragma unroll
        for (int i = 0; i < 6; i++) {
          const int idx = tid + i * 256;
          pcap[i] = *(const float4*)(capB + (idx >> 5) * EMBED + kn + (idx & 31) * 4);
        }
      }
      if (act1) {
        const int qb = g1 * 16;
#pragma unroll 8
        for (int qq = 0; qq < 16; qq++) {
          const int q = qb + qq;
          float4 av[4];
#pragma unroll
          for (int a = 0; a < 4; a++)
            av[a] = *(const float4*)&bufA[(r0 + a) * 132 + (q ^ si) * 4];
#pragma unroll
          for (int b = 0; b < 4; b++) {
            const float4 bv = *(const float4*)&bufB[(w0 + b) * 132 + (q ^ sc) * 4];
#pragma unroll
            for (int a = 0; a < 4; a++)
              acc1[a][b] += av[a].x * bv.x + av[a].y * bv.y +
                            av[a].z * bv.z + av[a].w * bv.w;
          }
        }
      }
      __syncthreads();   // all reads of chunk kc done before next write
    }
  }
  {
    float* part = bufA;  // 2 groups * 1728 = 3456 floats (img dead)
    if (act1) {
#pragma unroll
      for (int a = 0; a < 4; a++)
#pragma unroll
        for (int b = 0; b < 4; b++)
          part[g1 * 1728 + (r0 + a) * 48 + (w0 + b)] = acc1[a][b];
    }
    __syncthreads();
    for (int p = tid; p < 1728; p += 256) {
      float s = part[p] + part[p + 1728];
      const int r = p / 48, w = p % 48;
      const int cc = w / 24, wl = w % 24;
      bufC[cc * 1008 + r * 28 + wl] = (s > 0.f) ? s : 0.1f * s;  // leaky 0.1
    }
    __syncthreads();
  }

  // ============ stage 2 + stage-3 chunk-0 prefetch (overlapped) ============
  for (int idx = tid; idx < 36 * 32; idx += 256) {
    const int r = idx >> 5, q = idx & 31;
    *(float4*)&bufA[r * 132 + (q ^ ((r >> 2) & 7)) * 4] =
        *(const float4*)(imgN + r * EMBED + q * 4);
  }
  if (tid < 72) {
    const int cc = tid / 36, r = tid % 36;
    float* row = bufC + cc * 1008 + r * 28;
    float s = 0.f;
    for (int w = 0; w < 24; w++) { float x = row[w]; s += x * x; }
    const float inv = 1.f / (sqrtf(s) + EPSV);
    for (int w = 0; w < 24; w++) row[w] *= inv;
  }
  __syncthreads();
  if (tid < 48) {
    const int cc = tid / 24, w = tid % 24;
    float* colb = bufC + cc * 1008 + w;
    float m = -1e30f;
    for (int r = 0; r < 36; r++) m = fmaxf(m, colb[r * 28]);
    float ssum = 0.f;
    for (int r = 0; r < 36; r++) {
      float e = expf(4.0f * (colb[r * 28] - m));
      colb[r * 28] = e; ssum += e;
    }
    const float inv = 1.0f / ssum;
    for (int r = 0; r < 36; r++) colb[r * 28] *= inv;
  }
  __syncthreads();   // orders: softmax done AND chunk-0 staging done

  // ============ stage 3: double-buffered wctx + block cosine -> tnode ============
  const int wg3 = (tid >> 5) * 3;
  const int dq = tid & 31;
  {
    float* tn0 = bufB;          // [24][33]
    float* tn1 = bufB + 792;
    for (int kc = 0; kc < 8; kc++) {
      const int k0 = kc * 128;
      float* cur = (kc & 1) ? (bufB + 1584) : bufA;
      if (kc < 7) {
        float* nxt = (kc & 1) ? bufA : (bufB + 1584);
        const int kn = k0 + 128;
        for (int idx = tid; idx < 36 * 32; idx += 256) {
          const int r = idx >> 5, q = idx & 31;
          *(float4*)&nxt[r * 132 + (q ^ ((r >> 2) & 7)) * 4] =
              *(const float4*)(imgN + r * EMBED + kn + q * 4);
        }
      }
      {
        float4 a00 = make_float4(0.f, 0.f, 0.f, 0.f), a01 = a00, a02 = a00;
        float4 a10 = a00, a11 = a00, a12 = a00;
#pragma unroll 4
        for (int r = 0; r < 36; r++) {
          float4 iv = *(const float4*)&cur[r * 132 + (dq ^ ((r >> 2) & 7)) * 4];
          const float* awr = bufC + r * 28 + wg3;
          const float b00 = awr[0],    b01 = awr[1],    b02 = awr[2];
          const float b10 = awr[1008], b11 = awr[1009], b12 = awr[1010];
          a00.x += b00 * iv.x; a00.y += b00 * iv.y; a00.z += b00 * iv.z; a00.w += b00 * iv.w;
          a01.x += b01 * iv.x; a01.y += b01 * iv.y; a01.z += b01 * iv.z; a01.w += b01 * iv.w;
          a02.x += b02 * iv.x; a02.y += b02 * iv.y; a02.z += b02 * iv.z; a02.w += b02 * iv.w;
          a10.x += b10 * iv.x; a10.y += b10 * iv.y; a10.z += b10 * iv.z; a10.w += b10 * iv.w;
          a11.x += b11 * iv.x; a11.y += b11 * iv.y; a11.z += b11 * iv.z; a11.w += b11 * iv.w;
          a12.x += b12 * iv.x; a12.y += b12 * iv.y; a12.z += b12 * iv.z; a12.w += b12 * iv.w;
        }
        // cap slices AFTER the r-loop (pressure)
        const float* cp0 = capB + wg3 * EMBED + k0 + dq * 4;
        const float* cp1 = capB + (24 + wg3) * EMBED + k0 + dq * 4;
        float4 cv00 = *(const float4*)(cp0);
        float4 cv01 = *(const float4*)(cp0 + EMBED);
        float4 cv02 = *(const float4*)(cp0 + 2 * EMBED);
        float4 cv10 = *(const float4*)(cp1);
        float4 cv11 = *(const float4*)(cp1 + EMBED);
        float4 cv12 = *(const float4*)(cp1 + 2 * EMBED);
        float nu00 = a00.x*cv00.x + a00.y*cv00.y + a00.z*cv00.z + a00.w*cv00.w;
        float nu01 = a01.x*cv01.x + a01.y*cv01.y + a01.z*cv01.z + a01.w*cv01.w;
        float nu02 = a02.x*cv02.x + a02.y*cv02.y + a02.z*cv02.z + a02.w*cv02.w;
        float nu10 = a10.x*cv10.x + a10.y*cv10.y + a10.z*cv10.z + a10.w*cv10.w;
        float nu11 = a11.x*cv11.x + a11.y*cv11.y + a11.z*cv11.z + a11.w*cv11.w;
        float nu12 = a12.x*cv12.x + a12.y*cv12.y + a12.z*cv12.z + a12.w*cv12.w;
        float cz00 = a00.x*a00.x + a00.y*a00.y + a00.z*a00.z + a00.w*a00.w;
        float cz01 = a01.x*a01.x + a01.y*a01.y + a01.z*a01.z + a01.w*a01.w;
        float cz02 = a02.x*a02.x + a02.y*a02.y + a02.z*a02.z + a02.w*a02.w;
        float cz10 = a10.x*a10.x + a10.y*a10.y + a10.z*a10.z + a10.w*a10.w;
        float cz11 = a11.x*a11.x + a11.y*a11.y + a11.z*a11.z + a11.w*a11.w;
        float cz12 = a12.x*a12.x + a12.y*a12.y + a12.z*a12.z + a12.w*a12.w;
#pragma unroll
        for (int m = 1; m < 8; m <<= 1) {
          nu00 += __shfl_xor(nu00, m); cz00 += __shfl_xor(cz00, m);
          nu01 += __shfl_xor(nu01, m); cz01 += __shfl_xor(cz01, m);
          nu02 += __shfl_xor(nu02, m); cz02 += __shfl_xor(cz02, m);
          nu10 += __shfl_xor(nu10, m); cz10 += __shfl_xor(cz10, m);
          nu11 += __shfl_xor(nu11, m); cz11 += __shfl_xor(cz11, m);
          nu12 += __shfl_xor(nu12, m); cz12 += __shfl_xor(cz12, m);
        }
        if ((dq & 7) == 0) {
          const int f = (k0 >> 5) + (dq >> 3);
          const float* q0 = ws + WS_QN + (c0 * 24 + wg3) * 32 + f;
          const float* q1 = q0 + 24 * 32;
          tn0[(wg3 + 0) * 33 + f] = nu00 / fmaxf(q0[0]  * sqrtf(cz00), EPSV);
          tn0[(wg3 + 1) * 33 + f] = nu01 / fmaxf(q0[32] * sqrtf(cz01), EPSV);
          tn0[(wg3 + 2) * 33 + f] = nu02 / fmaxf(q0[64] * sqrtf(cz02), EPSV);
          tn1[(wg3 + 0) * 33 + f] = nu10 / fmaxf(q1[0]  * sqrtf(cz10), EPSV);
          tn1[(wg3 + 1) * 33 + f] = nu11 / fmaxf(q1[32] * sqrtf(cz11), EPSV);
          tn1[(wg3 + 2) * 33 + f] = nu12 / fmaxf(q1[64] * sqrtf(cz12), EPSV);
        }
      }
      __syncthreads();   // next buffer staged; cur free for overwrite
    }
  }

  // ============ stage 4: graph-conv + MLP, BOTH captions per phase ============
  float* W1t = bufA;            // 64x68; staged ONCE
  float* hid2 = bufB + 1584;    // 2 x 24x68 (img chunk B dead)
  float* Ss  = bufC;            // 384: S for c0,c1 (attn dead)
  float* w2s = bufC + 384;
  float* b1s = bufC + 448;
  float* sred = bufC + 512;     // 48
  for (int idx = tid; idx < 4096; idx += 256) {
    const int j = idx >> 6, col = idx & 63;
    W1t[col * 68 + j] = ws[WS_W1 + idx];
  }
  for (int p = tid; p < 384; p += 256) Ss[p] = ws[WS_S + c0 * 192 + p];
  if (tid < 64) w2s[tid] = ws[WS_W2 + tid];
  else if (tid < 128) b1s[tid - 64] = out1_b[tid - 64];
  __syncthreads();

  // hidden for BOTH captions (independent regions, no barrier between)
  for (int cc = 0; cc < 2; cc++) {
    const float* tnp = bufB + cc * 792;
    float* hh = hid2 + cc * 1632;
    for (int p = tid; p < 1536; p += 256) {
      const int w = p >> 6, col = p & 63, k = col >> 3, o = col & 7;
      const float* cw = conv_w + k * 256 + o;
      float tacc = 0.f;
#pragma unroll 8
      for (int f = 0; f < 32; f++) tacc += tnp[w * 33 + f] * cw[f * 8];
      hh[w * 68 + col] = Ss[cc * 192 + w * 8 + k] * tacc;
    }
  }
  __syncthreads();

  // h = tanh(hidden @ W1^T + b1), 768 items (both captions)
  float hv[3][4];
  {
    int pc = 0;
    for (int p = tid; p < 768; p += 256, pc++) {
      const int cc = p / 384, pl = p % 384;
      const int w = pl >> 4, j0 = (pl & 15) * 4;
      const float* hh = hid2 + cc * 1632;
      float ax = b1s[j0 + 0], ay = b1s[j0 + 1], az = b1s[j0 + 2], aww = b1s[j0 + 3];
#pragma unroll 4
      for (int col = 0; col < 64; col += 4) {
        float4 h4 = *(const float4*)&hh[w * 68 + col];
        float4 wv0 = *(const float4*)&W1t[(col + 0) * 68 + j0];
        float4 wv1 = *(const float4*)&W1t[(col + 1) * 68 + j0];
        float4 wv2 = *(const float4*)&W1t[(col + 2) * 68 + j0];
        float4 wv3 = *(const float4*)&W1t[(col + 3) * 68 + j0];
        ax  += h4.x * wv0.x + h4.y * wv1.x + h4.z * wv2.x + h4.w * wv3.x;
        ay  += h4.x * wv0.y + h4.y * wv1.y + h4.z * wv2.y + h4.w * wv3.y;
        az  += h4.x * wv0.z + h4.y * wv1.z + h4.z * wv2.z + h4.w * wv3.z;
        aww += h4.x * wv0.w + h4.y * wv1.w + h4.z * wv2.w + h4.w * wv3.w;
      }
      hv[pc][0] = tanhf(ax); hv[pc][1] = tanhf(ay);
      hv[pc][2] = tanhf(az); hv[pc][3] = tanhf(aww);
    }
    __syncthreads();  // all reads of hid2 complete before overwrite
    pc = 0;
    for (int p = tid; p < 768; p += 256, pc++) {
      const int cc = p / 384, pl = p % 384;
      const int w = pl >> 4, j0 = (pl & 15) * 4;
      float* hh = hid2 + cc * 1632;
      hh[w * 68 + j0 + 0] = hv[pc][0]; hh[w * 68 + j0 + 1] = hv[pc][1];
      hh[w * 68 + j0 + 2] = hv[pc][2]; hh[w * 68 + j0 + 3] = hv[pc][3];
    }
    __syncthreads();
  }

  // s[w] both captions; then per-caption mean
  if (tid < 48) {
    const int cc = tid / 24, w = tid % 24;
    const float* hh = hid2 + cc * 1632;
    float sv = out2_b[0];
    for (int j = 0; j < 64; j++) sv += hh[w * 68 + j] * w2s[j];
    sred[tid] = sv;
  }
  __syncthreads();
  if (tid < 2) {
    float s = 0.f;
    for (int w = 0; w < 24; w++) s += sred[tid * 24 + w];
    out[n * 32 + c0 + tid] = s * (1.0f / 24.0f);
  }
}

// ---------------------------------------------------------------------------
extern "C" void kernel_launch(void* const* d_in, const int* in_sizes, int n_in,
                              void* d_out, int out_size, void* d_ws, size_t ws_size,
                              hipStream_t stream) {
  const float* images   = (const float*)d_in[0];
  const float* captions = (const float*)d_in[1];
  const int*   depends  = (const int*)d_in[2];
  // d_in[3] cap_lens: unused by reference math (all == N_WORD)
  const float* mean_k   = (const float*)d_in[4];
  const float* prec_k   = (const float*)d_in[5];
  const float* conv_w   = (const float*)d_in[6];
  const float* out1_v   = (const float*)d_in[7];
  const float* out1_g   = (const float*)d_in[8];
  const float* out1_b   = (const float*)d_in[9];
  const float* out2_v   = (const float*)d_in[10];
  const float* out2_g   = (const float*)d_in[11];
  const float* out2_b   = (const float*)d_in[12];
  float* ws  = (float*)d_ws;
  float* out = (float*)d_out;

  cap_prep_k<<<dim3(33), dim3(256), 0, stream>>>(
      captions, depends, mean_k, prec_k, out1_v, out1_g, out2_v, out2_g, ws);
  main_k<<<dim3(N_IMAGE * 16), dim3(256), 0, stream>>>(
      images, captions, conv_w, out1_b, out2_b, ws, out);
}

// Round 21
// 484.238 us; speedup vs baseline: 1.1288x; 1.1288x over previous
//
#include <hip/hip_runtime.h>
#include <math.h>

// Problem constants
#define N_IMAGE   128
#define N_CAPTION 32
#define N_REGION  36
#define N_WORD    24
#define EMBED     1024
#define EPSV      1e-8f

// Workspace layout (float offsets)
#define WS_W1 0            // 64*64 weight-normed out1 W
#define WS_W2 4096         // 64 weight-normed out2 row
#define WS_S  4160         // 32 captions * 24 words * 8 kernels
#define WS_QN 10304        // 32 captions * 24 words * 32 blocks

// ---------------------------------------------------------------------------
// Kernel 1+2 merged: block 32 = weight-norm; blocks 0..31 = per-caption
// precompute. (Saves one launch; R18's regression was main_k only.)
// ---------------------------------------------------------------------------
__global__ __launch_bounds__(256) void cap_prep_k(
    const float* __restrict__ captions, const int* __restrict__ depends,
    const float* __restrict__ mean_k, const float* __restrict__ prec_k,
    const float* __restrict__ v1, const float* __restrict__ g1,
    const float* __restrict__ v2, const float* __restrict__ g2,
    float* __restrict__ ws) {
  __shared__ __align__(16) float capT[24][132];
  __shared__ float partB[2304];   // 4 groups * 576
  __shared__ float wsL[24][25];
  __shared__ float adjL[24][24];

  const int tid = threadIdx.x;
  if (blockIdx.x == 32) {   // weight-norm branch (no barriers in this path)
    if (tid < 64) {
      const int j = tid;
      float s = 0.f;
      for (int c0 = 0; c0 < 64; c0++) { float x = v1[j * 64 + c0]; s += x * x; }
      const float sc = g1[j] / sqrtf(s);
      for (int c0 = 0; c0 < 64; c0++) ws[WS_W1 + j * 64 + c0] = v1[j * 64 + c0] * sc;
      float s2 = 0.f;
      for (int c0 = 0; c0 < 64; c0++) { float x = v2[c0]; s2 += x * x; }
      ws[WS_W2 + j] = v2[j] * (g2[0] / sqrtf(s2));
    }
    return;
  }

  const int c = blockIdx.x;
  const float* capC = captions + c * N_WORD * EMBED;

  const int g = tid / 36, t = tid % 36;
  const int i0 = (t / 6) * 4, j0 = (t % 6) * 4;
  const bool act = tid < 144;
  float acc[4][4] = {};
  for (int k0 = 0; k0 < EMBED; k0 += 128) {
    for (int idx = tid; idx < 24 * 32; idx += 256) {
      int r = idx >> 5, q = idx & 31;
      *(float4*)&capT[r][q * 4] = *(const float4*)(capC + r * EMBED + k0 + q * 4);
    }
    __syncthreads();
    if (act) {
#pragma unroll
      for (int q8 = 0; q8 < 8; q8++) {
        const int q = g * 8 + q8;
        float4 av[4], bv[4];
#pragma unroll
        for (int a = 0; a < 4; a++) av[a] = *(const float4*)&capT[i0 + a][q * 4];
#pragma unroll
        for (int b = 0; b < 4; b++) bv[b] = *(const float4*)&capT[j0 + b][q * 4];
#pragma unroll
        for (int a = 0; a < 4; a++)
#pragma unroll
          for (int b = 0; b < 4; b++)
            acc[a][b] += av[a].x * bv[b].x + av[a].y * bv[b].y +
                         av[a].z * bv[b].z + av[a].w * bv[b].w;
      }
    }
    __syncthreads();
  }
  if (act)
#pragma unroll
    for (int a = 0; a < 4; a++)
#pragma unroll
      for (int b = 0; b < 4; b++)
        partB[g * 576 + (i0 + a) * 24 + (j0 + b)] = acc[a][b];
  __syncthreads();
  for (int p = tid; p < 576; p += 256)
    wsL[p / 24][p % 24] = partB[p] + partB[p + 576] + partB[p + 1152] + partB[p + 1728];
  {
    float* ap = &adjL[0][0];
    for (int p = tid; p < 576; p += 256) ap[p] = 0.f;
  }
  __syncthreads();
  if (tid < 24) {
    const int i = tid;
    float m = -1e30f;
    for (int j = 0; j < 24; j++) m = fmaxf(m, wsL[i][j]);
    float ssum = 0.f;
    for (int j = 0; j < 24; j++) {
      float e = expf(4.0f * (wsL[i][j] - m));
      wsL[i][j] = e; ssum += e;
    }
    float inv = 1.0f / ssum;
    for (int j = 0; j < 24; j++) wsL[i][j] *= inv;
  }
  __syncthreads();
  if (tid >= 1 && tid < 23) {
    int r = depends[c * 46 + tid * 2];
    int cc = depends[c * 46 + tid * 2 + 1];
    if ((unsigned)r < 24u && (unsigned)cc < 24u) {
      adjL[r][cc] = 1.f;
      adjL[cc][r] = 1.f;
    }
  }
  __syncthreads();
  if (tid < 24) adjL[tid][tid] += 1.f;
  __syncthreads();
  if (tid < 24) {
    const int i = tid;
    float mk[8], pk2[8];
#pragma unroll
    for (int k = 0; k < 8; k++) {
      mk[k] = mean_k[k];
      float p = prec_k[k];
      pk2[k] = 1e-14f + p * p;
    }
    float s2 = 0.f;
    for (int j = 0; j < 24; j++) {
      float a = adjL[i][j] * wsL[i][j];
      s2 += a * a;
    }
    const float inv = 1.0f / (sqrtf(s2) + EPSV);
    float accS[8] = {};
    for (int j = 0; j < 24; j++) {
      const float adj_ij = adjL[i][j];
      if (adj_ij != 0.f) {
        const float nb = adj_ij * wsL[i][j] * inv;
        float wk[8], ssum = 0.f;
#pragma unroll
        for (int k = 0; k < 8; k++) {
          float d = nb - mk[k];
          wk[k] = expf(-0.5f * d * d / pk2[k]);
          ssum += wk[k];
        }
        const float invs = adj_ij / ssum;
#pragma unroll
        for (int k = 0; k < 8; k++) accS[k] += wk[k] * invs;
      }
    }
#pragma unroll
    for (int k = 0; k < 8; k++) ws[WS_S + (c * 24 + i) * 8 + k] = accS[k];
  }
  for (int p = tid; p < 768; p += 256) {
    const int w = p >> 5, f = p & 31;
    const float* q = capC + w * EMBED + f * 32;
    float s = 0.f;
#pragma unroll
    for (int d = 0; d < 32; d += 4) {
      float4 v = *(const float4*)(q + d);
      s += v.x * v.x + v.y * v.y + v.z * v.z + v.w * v.w;
    }
    ws[WS_QN + (c * 24 + w) * 32 + f] = sqrtf(s);
  }
}

// ---------------------------------------------------------------------------
// Kernel 3: main — one block per (image n, caption-PAIR c0,c0+1). R21
// (resubmit; R19 and R20 benches were GPUAcquisitionTimeout — no data):
//   R18 post-mortem: stage-1 register-prefetch SPILLED (WRITE 64KB->642MB,
//   VGPR pinned at 68 — compiler put pimg/pcap arrays held across the
//   barrier in scratch, not registers). T14-via-source-arrays is closed on
//   this toolchain. This = R17 main_k VERBATIM (best: 423us, VGPR 68, zero
//   scratch) + merged front kernel (one less launch).
// ---------------------------------------------------------------------------
__global__ __launch_bounds__(256, 2) void main_k(
    const float* __restrict__ images, const float* __restrict__ captions,
    const float* __restrict__ conv_w, const float* __restrict__ out1_b,
    const float* __restrict__ out2_b, const float* __restrict__ ws,
    float* __restrict__ out) {
  // bufA: img chunk A (swizzled 36x132) / split-K partials (3456) / W1t (64x68)
  // bufB: capT 2 captions (48x132) / {tnode[2][24][33], img chunk B / hid2}
  // bufC: attn [2][36][28] / {Ss[384], w2s[64], b1s[64], sred[48]}
  __shared__ __align__(16) float bufA[36 * 132];      // 19008 B
  __shared__ __align__(16) float bufB[48 * 132];      // 25344 B
  __shared__ __align__(16) float bufC[2 * 36 * 28];   //  8064 B => 52416 B

  const int tid = threadIdx.x;
  const int bid = blockIdx.x;
  const int n = bid >> 4, c0 = (bid & 15) * 2;
  const float* imgN = images + n * N_REGION * EMBED;
  const float* capB = captions + c0 * N_WORD * EMBED;  // 48 contiguous rows

  // ============ stage 1: attn_raw = leaky_relu(img @ [cap0;cap1]^T) ============
  // 216 active threads, 2-way split-K, 4x4 register tiles over 36x48 outputs.
  const int g1 = tid / 108, t1 = tid % 108;
  const int r0 = (t1 / 12) * 4, w0 = (t1 % 12) * 4;
  const bool act1 = tid < 216;
  const int si = (r0 >> 2) & 7, sc = (w0 >> 2) & 7;   // bank swizzles
  float acc1[4][4] = {};

  for (int k0 = 0; k0 < EMBED; k0 += 128) {
    for (int idx = tid; idx < 36 * 32; idx += 256) {
      const int r = idx >> 5, q = idx & 31;
      *(float4*)&bufA[r * 132 + (q ^ ((r >> 2) & 7)) * 4] =
          *(const float4*)(imgN + r * EMBED + k0 + q * 4);
    }
    for (int idx = tid; idx < 48 * 32; idx += 256) {
      const int r = idx >> 5, q = idx & 31;
      *(float4*)&bufB[r * 132 + (q ^ ((r >> 2) & 7)) * 4] =
          *(const float4*)(capB + r * EMBED + k0 + q * 4);
    }
    __syncthreads();
    if (act1) {
#pragma unroll 8
      for (int qq = 0; qq < 16; qq++) {
        const int q = g1 * 16 + qq;
        float4 av[4];
#pragma unroll
        for (int a = 0; a < 4; a++)
          av[a] = *(const float4*)&bufA[(r0 + a) * 132 + (q ^ si) * 4];
#pragma unroll
        for (int b = 0; b < 4; b++) {
          const float4 bv = *(const float4*)&bufB[(w0 + b) * 132 + (q ^ sc) * 4];
#pragma unroll
          for (int a = 0; a < 4; a++)
            acc1[a][b] += av[a].x * bv.x + av[a].y * bv.y +
                          av[a].z * bv.z + av[a].w * bv.w;
        }
      }
    }
    __syncthreads();
  }
  {
    float* part = bufA;  // 2 groups * 1728 = 3456 floats (img dead)
    if (act1) {
#pragma unroll
      for (int a = 0; a < 4; a++)
#pragma unroll
        for (int b = 0; b < 4; b++)
          part[g1 * 1728 + (r0 + a) * 48 + (w0 + b)] = acc1[a][b];
    }
    __syncthreads();
    for (int p = tid; p < 1728; p += 256) {
      float s = part[p] + part[p + 1728];
      const int r = p / 48, w = p % 48;
      const int cc = w / 24, wl = w % 24;
      bufC[cc * 1008 + r * 28 + wl] = (s > 0.f) ? s : 0.1f * s;  // leaky 0.1
    }
    __syncthreads();
  }

  // ============ stage 2 + stage-3 chunk-0 prefetch (overlapped) ============
  // Staging writes bufA (partials dead); stage-2 math touches bufC only.
  for (int idx = tid; idx < 36 * 32; idx += 256) {
    const int r = idx >> 5, q = idx & 31;
    *(float4*)&bufA[r * 132 + (q ^ ((r >> 2) & 7)) * 4] =
        *(const float4*)(imgN + r * EMBED + q * 4);
  }
  if (tid < 72) {
    const int cc = tid / 36, r = tid % 36;
    float* row = bufC + cc * 1008 + r * 28;
    float s = 0.f;
    for (int w = 0; w < 24; w++) { float x = row[w]; s += x * x; }
    const float inv = 1.f / (sqrtf(s) + EPSV);
    for (int w = 0; w < 24; w++) row[w] *= inv;
  }
  __syncthreads();
  if (tid < 48) {
    const int cc = tid / 24, w = tid % 24;
    float* colb = bufC + cc * 1008 + w;
    float m = -1e30f;
    for (int r = 0; r < 36; r++) m = fmaxf(m, colb[r * 28]);
    float ssum = 0.f;
    for (int r = 0; r < 36; r++) {
      float e = expf(4.0f * (colb[r * 28] - m));
      colb[r * 28] = e; ssum += e;
    }
    const float inv = 1.0f / ssum;
    for (int r = 0; r < 36; r++) colb[r * 28] *= inv;
  }
  __syncthreads();   // orders: softmax done AND chunk-0 staging done

  // ============ stage 3: double-buffered wctx + block cosine -> tnode ============
  // buf0 = bufA, buf1 = bufB+1584 (exactly 4752 floats after tnode[2][24][33]).
  const int wg3 = (tid >> 5) * 3;
  const int dq = tid & 31;
  {
    float* tn0 = bufB;          // [24][33]
    float* tn1 = bufB + 792;
    for (int kc = 0; kc < 8; kc++) {
      const int k0 = kc * 128;
      float* cur = (kc & 1) ? (bufB + 1584) : bufA;
      if (kc < 7) {
        float* nxt = (kc & 1) ? bufA : (bufB + 1584);
        const int kn = k0 + 128;
        for (int idx = tid; idx < 36 * 32; idx += 256) {
          const int r = idx >> 5, q = idx & 31;
          *(float4*)&nxt[r * 132 + (q ^ ((r >> 2) & 7)) * 4] =
              *(const float4*)(imgN + r * EMBED + kn + q * 4);
        }
      }
      {
        float4 a00 = make_float4(0.f, 0.f, 0.f, 0.f), a01 = a00, a02 = a00;
        float4 a10 = a00, a11 = a00, a12 = a00;
#pragma unroll 4
        for (int r = 0; r < 36; r++) {
          float4 iv = *(const float4*)&cur[r * 132 + (dq ^ ((r >> 2) & 7)) * 4];
          const float* awr = bufC + r * 28 + wg3;
          const float b00 = awr[0],    b01 = awr[1],    b02 = awr[2];
          const float b10 = awr[1008], b11 = awr[1009], b12 = awr[1010];
          a00.x += b00 * iv.x; a00.y += b00 * iv.y; a00.z += b00 * iv.z; a00.w += b00 * iv.w;
          a01.x += b01 * iv.x; a01.y += b01 * iv.y; a01.z += b01 * iv.z; a01.w += b01 * iv.w;
          a02.x += b02 * iv.x; a02.y += b02 * iv.y; a02.z += b02 * iv.z; a02.w += b02 * iv.w;
          a10.x += b10 * iv.x; a10.y += b10 * iv.y; a10.z += b10 * iv.z; a10.w += b10 * iv.w;
          a11.x += b11 * iv.x; a11.y += b11 * iv.y; a11.z += b11 * iv.z; a11.w += b11 * iv.w;
          a12.x += b12 * iv.x; a12.y += b12 * iv.y; a12.z += b12 * iv.z; a12.w += b12 * iv.w;
        }
        // cap slices AFTER the r-loop (pressure)
        const float* cp0 = capB + wg3 * EMBED + k0 + dq * 4;
        const float* cp1 = capB + (24 + wg3) * EMBED + k0 + dq * 4;
        float4 cv00 = *(const float4*)(cp0);
        float4 cv01 = *(const float4*)(cp0 + EMBED);
        float4 cv02 = *(const float4*)(cp0 + 2 * EMBED);
        float4 cv10 = *(const float4*)(cp1);
        float4 cv11 = *(const float4*)(cp1 + EMBED);
        float4 cv12 = *(const float4*)(cp1 + 2 * EMBED);
        float nu00 = a00.x*cv00.x + a00.y*cv00.y + a00.z*cv00.z + a00.w*cv00.w;
        float nu01 = a01.x*cv01.x + a01.y*cv01.y + a01.z*cv01.z + a01.w*cv01.w;
        float nu02 = a02.x*cv02.x + a02.y*cv02.y + a02.z*cv02.z + a02.w*cv02.w;
        float nu10 = a10.x*cv10.x + a10.y*cv10.y + a10.z*cv10.z + a10.w*cv10.w;
        float nu11 = a11.x*cv11.x + a11.y*cv11.y + a11.z*cv11.z + a11.w*cv11.w;
        float nu12 = a12.x*cv12.x + a12.y*cv12.y + a12.z*cv12.z + a12.w*cv12.w;
        float cz00 = a00.x*a00.x + a00.y*a00.y + a00.z*a00.z + a00.w*a00.w;
        float cz01 = a01.x*a01.x + a01.y*a01.y + a01.z*a01.z + a01.w*a01.w;
        float cz02 = a02.x*a02.x + a02.y*a02.y + a02.z*a02.z + a02.w*a02.w;
        float cz10 = a10.x*a10.x + a10.y*a10.y + a10.z*a10.z + a10.w*a10.w;
        float cz11 = a11.x*a11.x + a11.y*a11.y + a11.z*a11.z + a11.w*a11.w;
        float cz12 = a12.x*a12.x + a12.y*a12.y + a12.z*a12.z + a12.w*a12.w;
#pragma unroll
        for (int m = 1; m < 8; m <<= 1) {
          nu00 += __shfl_xor(nu00, m); cz00 += __shfl_xor(cz00, m);
          nu01 += __shfl_xor(nu01, m); cz01 += __shfl_xor(cz01, m);
          nu02 += __shfl_xor(nu02, m); cz02 += __shfl_xor(cz02, m);
          nu10 += __shfl_xor(nu10, m); cz10 += __shfl_xor(cz10, m);
          nu11 += __shfl_xor(nu11, m); cz11 += __shfl_xor(cz11, m);
          nu12 += __shfl_xor(nu12, m); cz12 += __shfl_xor(cz12, m);
        }
        if ((dq & 7) == 0) {
          const int f = (k0 >> 5) + (dq >> 3);
          const float* q0 = ws + WS_QN + (c0 * 24 + wg3) * 32 + f;
          const float* q1 = q0 + 24 * 32;
          tn0[(wg3 + 0) * 33 + f] = nu00 / fmaxf(q0[0]  * sqrtf(cz00), EPSV);
          tn0[(wg3 + 1) * 33 + f] = nu01 / fmaxf(q0[32] * sqrtf(cz01), EPSV);
          tn0[(wg3 + 2) * 33 + f] = nu02 / fmaxf(q0[64] * sqrtf(cz02), EPSV);
          tn1[(wg3 + 0) * 33 + f] = nu10 / fmaxf(q1[0]  * sqrtf(cz10), EPSV);
          tn1[(wg3 + 1) * 33 + f] = nu11 / fmaxf(q1[32] * sqrtf(cz11), EPSV);
          tn1[(wg3 + 2) * 33 + f] = nu12 / fmaxf(q1[64] * sqrtf(cz12), EPSV);
        }
      }
      __syncthreads();   // next buffer staged; cur free for overwrite
    }
  }

  // ============ stage 4: graph-conv + MLP, BOTH captions per phase ============
  float* W1t = bufA;            // 64x68; staged ONCE
  float* hid2 = bufB + 1584;    // 2 x 24x68 (img chunk B dead)
  float* Ss  = bufC;            // 384: S for c0,c1 (attn dead)
  float* w2s = bufC + 384;
  float* b1s = bufC + 448;
  float* sred = bufC + 512;     // 48
  for (int idx = tid; idx < 4096; idx += 256) {
    const int j = idx >> 6, col = idx & 63;
    W1t[col * 68 + j] = ws[WS_W1 + idx];
  }
  for (int p = tid; p < 384; p += 256) Ss[p] = ws[WS_S + c0 * 192 + p];
  if (tid < 64) w2s[tid] = ws[WS_W2 + tid];
  else if (tid < 128) b1s[tid - 64] = out1_b[tid - 64];
  __syncthreads();

  // hidden for BOTH captions (independent regions, no barrier between)
  for (int cc = 0; cc < 2; cc++) {
    const float* tnp = bufB + cc * 792;
    float* hh = hid2 + cc * 1632;
    for (int p = tid; p < 1536; p += 256) {
      const int w = p >> 6, col = p & 63, k = col >> 3, o = col & 7;
      const float* cw = conv_w + k * 256 + o;
      float tacc = 0.f;
#pragma unroll 8
      for (int f = 0; f < 32; f++) tacc += tnp[w * 33 + f] * cw[f * 8];
      hh[w * 68 + col] = Ss[cc * 192 + w * 8 + k] * tacc;
    }
  }
  __syncthreads();

  // h = tanh(hidden @ W1^T + b1), 768 items (both captions)
  float hv[3][4];
  {
    int pc = 0;
    for (int p = tid; p < 768; p += 256, pc++) {
      const int cc = p / 384, pl = p % 384;
      const int w = pl >> 4, j0 = (pl & 15) * 4;
      const float* hh = hid2 + cc * 1632;
      float ax = b1s[j0 + 0], ay = b1s[j0 + 1], az = b1s[j0 + 2], aww = b1s[j0 + 3];
#pragma unroll 4
      for (int col = 0; col < 64; col += 4) {
        float4 h4 = *(const float4*)&hh[w * 68 + col];
        float4 wv0 = *(const float4*)&W1t[(col + 0) * 68 + j0];
        float4 wv1 = *(const float4*)&W1t[(col + 1) * 68 + j0];
        float4 wv2 = *(const float4*)&W1t[(col + 2) * 68 + j0];
        float4 wv3 = *(const float4*)&W1t[(col + 3) * 68 + j0];
        ax  += h4.x * wv0.x + h4.y * wv1.x + h4.z * wv2.x + h4.w * wv3.x;
        ay  += h4.x * wv0.y + h4.y * wv1.y + h4.z * wv2.y + h4.w * wv3.y;
        az  += h4.x * wv0.z + h4.y * wv1.z + h4.z * wv2.z + h4.w * wv3.z;
        aww += h4.x * wv0.w + h4.y * wv1.w + h4.z * wv2.w + h4.w * wv3.w;
      }
      hv[pc][0] = tanhf(ax); hv[pc][1] = tanhf(ay);
      hv[pc][2] = tanhf(az); hv[pc][3] = tanhf(aww);
    }
    __syncthreads();  // all reads of hid2 complete before overwrite
    pc = 0;
    for (int p = tid; p < 768; p += 256, pc++) {
      const int cc = p / 384, pl = p % 384;
      const int w = pl >> 4, j0 = (pl & 15) * 4;
      float* hh = hid2 + cc * 1632;
      hh[w * 68 + j0 + 0] = hv[pc][0]; hh[w * 68 + j0 + 1] = hv[pc][1];
      hh[w * 68 + j0 + 2] = hv[pc][2]; hh[w * 68 + j0 + 3] = hv[pc][3];
    }
    __syncthreads();
  }

  // s[w] both captions; then per-caption mean
  if (tid < 48) {
    const int cc = tid / 24, w = tid % 24;
    const float* hh = hid2 + cc * 1632;
    float sv = out2_b[0];
    for (int j = 0; j < 64; j++) sv += hh[w * 68 + j] * w2s[j];
    sred[tid] = sv;
  }
  __syncthreads();
  if (tid < 2) {
    float s = 0.f;
    for (int w = 0; w < 24; w++) s += sred[tid * 24 + w];
    out[n * 32 + c0 + tid] = s * (1.0f / 24.0f);
  }
}

// ---------------------------------------------------------------------------
extern "C" void kernel_launch(void* const* d_in, const int* in_sizes, int n_in,
                              void* d_out, int out_size, void* d_ws, size_t ws_size,
                              hipStream_t stream) {
  const float* images   = (const float*)d_in[0];
  const float* captions = (const float*)d_in[1];
  const int*   depends  = (const int*)d_in[2];
  // d_in[3] cap_lens: unused by reference math (all == N_WORD)
  const float* mean_k   = (const float*)d_in[4];
  const float* prec_k   = (const float*)d_in[5];
  const float* conv_w   = (const float*)d_in[6];
  const float* out1_v   = (const float*)d_in[7];
  const float* out1_g   = (const float*)d_in[8];
  const float* out1_b   = (const float*)d_in[9];
  const float* out2_v   = (const float*)d_in[10];
  const float* out2_g   = (const float*)d_in[11];
  const float* out2_b   = (const float*)d_in[12];
  float* ws  = (float*)d_ws;
  float* out = (float*)d_out;

  cap_prep_k<<<dim3(33), dim3(256), 0, stream>>>(
      captions, depends, mean_k, prec_k, out1_v, out1_g, out2_v, out2_g, ws);
  main_k<<<dim3(N_IMAGE * 16), dim3(256), 0, stream>>>(
      images, captions, conv_w, out1_b, out2_b, ws, out);
}